// Round 3
// baseline (203.090 us; speedup 1.0000x reference)
//
#include <hip/hip_runtime.h>
#include <math.h>

#define BB   64
#define KK   128
#define HH   64
#define WW   64
#define HW   (HH*WW)      // 4096
#define NBOX 256
#define NCLS (BB*KK)      // 8192
#define NWAVE (NCLS + NBOX)

// One WAVE per plane (cls) or per box. No LDS, no barriers.
// Global wave id < NCLS  : max over plane -> BCE -> ws[w]
// Global wave id >= NCLS : box sigmoid in/out sums -> ws[w]
__global__ __launch_bounds__(256) void main_kernel(
    const float* __restrict__ cams,
    const float* __restrict__ gt,
    const int* __restrict__ box_b, const int* __restrict__ box_c,
    const int* __restrict__ by0, const int* __restrict__ by1,
    const int* __restrict__ bx0, const int* __restrict__ bx1,
    float* __restrict__ ws)
{
    const int gw   = (blockIdx.x * 256 + threadIdx.x) >> 6;   // global wave id
    const int lane = threadIdx.x & 63;
    if (gw >= NWAVE) return;

    if (gw < NCLS) {
        // ---- cls path: wave-max over 4096 floats (64 float4 per lane-pair group) ----
        const float4* p = (const float4*)(cams + (size_t)gw * HW);
        float m = -INFINITY;
        float4 v[8];
        #pragma unroll
        for (int j = 0; j < 8; ++j) v[j] = p[lane + 64 * j];
        #pragma unroll
        for (int j = 0; j < 8; ++j)
            m = fmaxf(m, fmaxf(fmaxf(v[j].x, v[j].y), fmaxf(v[j].z, v[j].w)));
        #pragma unroll
        for (int j = 0; j < 8; ++j) v[j] = p[lane + 64 * (8 + j)];
        #pragma unroll
        for (int j = 0; j < 8; ++j)
            m = fmaxf(m, fmaxf(fmaxf(v[j].x, v[j].y), fmaxf(v[j].z, v[j].w)));

        #pragma unroll
        for (int off = 32; off >= 1; off >>= 1)
            m = fmaxf(m, __shfl_down(m, off, 64));

        if (lane == 0) {
            float z = m;
            float y = gt[gw];
            ws[gw] = fmaxf(z, 0.f) - z * y + log1pf(expf(-fabsf(z)));  // stable BCE
        }
    } else {
        // ---- box path: one wave per box ----
        const int n  = gw - NCLS;
        const int b  = box_b[n];
        const int c  = box_c[n];
        const int y0 = by0[n], y1 = by1[n];
        const int x0 = bx0[n], x1 = bx1[n];
        const float4* p = (const float4*)(cams + ((size_t)b * KK + c) * HW);

        const int col0 = (4 * lane) & 63;    // 4 consecutive pixels, same row
        float ins = 0.f, outs = 0.f;
        #pragma unroll
        for (int batch = 0; batch < 2; ++batch) {
            float4 v[8];
            #pragma unroll
            for (int j = 0; j < 8; ++j) v[j] = p[lane + 64 * (8 * batch + j)];
            #pragma unroll
            for (int j = 0; j < 8; ++j) {
                const int row = (lane >> 4) + 4 * (8 * batch + j);
                const bool rin = (row >= y0) && (row < y1);
                float vv[4] = {v[j].x, v[j].y, v[j].z, v[j].w};
                #pragma unroll
                for (int e = 0; e < 4; ++e) {
                    float s = 1.f / (1.f + expf(-vv[e]));
                    const int cc = col0 + e;
                    const bool in = rin && (cc >= x0) && (cc < x1);
                    float d = s - 1.f;
                    if (in) ins  += d * d;
                    else    outs += s * s;
                }
            }
        }

        #pragma unroll
        for (int off = 32; off >= 1; off >>= 1) {
            ins  += __shfl_down(ins,  off, 64);
            outs += __shfl_down(outs, off, 64);
        }
        if (lane == 0) {
            float area = (float)((y1 - y0) * (x1 - x0));
            ws[gw] = ins / (area + 1e-6f) + outs / ((float)HW - area + 1e-6f);
        }
    }
}

// One block, 256 threads: sum 8192 BCE partials and 256 box partials.
__global__ __launch_bounds__(256) void reduce_kernel(
    const float* __restrict__ ws, float* __restrict__ out)
{
    const int t = threadIdx.x;
    __shared__ float red[8];

    float sc = 0.f;
    #pragma unroll
    for (int j = 0; j < NCLS / 256; ++j) sc += ws[t + 256 * j];
    float sb = ws[NCLS + t];

    #pragma unroll
    for (int off = 32; off >= 1; off >>= 1) {
        sc += __shfl_down(sc, off, 64);
        sb += __shfl_down(sb, off, 64);
    }
    const int wave = t >> 6;
    if ((t & 63) == 0) { red[wave] = sc; red[4 + wave] = sb; }
    __syncthreads();
    if (t == 0) {
        float cls = red[0] + red[1] + red[2] + red[3];
        float box = red[4] + red[5] + red[6] + red[7];
        out[0] = 1.0f * cls / (float)NCLS + 0.5f * box / (float)NBOX;
    }
}

extern "C" void kernel_launch(void* const* d_in, const int* in_sizes, int n_in,
                              void* d_out, int out_size, void* d_ws, size_t ws_size,
                              hipStream_t stream) {
    const float* cams = (const float*)d_in[0];
    const float* gt   = (const float*)d_in[1];
    const int*   bb   = (const int*)d_in[2];
    const int*   bc   = (const int*)d_in[3];
    const int*   y0   = (const int*)d_in[4];
    const int*   y1   = (const int*)d_in[5];
    const int*   x0   = (const int*)d_in[6];
    const int*   x1   = (const int*)d_in[7];
    float* ws  = (float*)d_ws;
    float* out = (float*)d_out;

    const int nblocks = (NWAVE * 64 + 255) / 256;   // 4 waves per block
    main_kernel<<<nblocks, 256, 0, stream>>>(cams, gt, bb, bc, y0, y1, x0, x1, ws);
    reduce_kernel<<<1, 256, 0, stream>>>(ws, out);
}